// Round 8
// baseline (112.287 us; speedup 1.0000x reference)
//
#include <hip/hip_runtime.h>
#include <hip/hip_bf16.h>

// Problem constants (fixed by the reference):
//   B=16, T=1024 -> BT=16384 rows; C=512 phones; A=4096 arcs; P=256 phonemes.
#define BT   16384
#define CDIM 512
#define ADIM 4096
#define PDIM 256

typedef __attribute__((ext_vector_type(8))) short  short8;   // 8 x bf16 (4 VGPRs)
typedef __attribute__((ext_vector_type(8))) unsigned short ushort8;
typedef __attribute__((ext_vector_type(4))) float  f32x4;    // 4 x fp32 acc

// fp32 -> bf16 round-to-nearest-even (values are positive finite)
__device__ __forceinline__ unsigned short bf16_rne(float f) {
    unsigned int u = __float_as_uint(f);
    u += 0x7FFFu + ((u >> 16) & 1u);
    return (unsigned short)(u >> 16);
}

// ---------------------------------------------------------------------------
// Kernel 1: W build. 16 blocks x 32 phones. Each block scans the 4096 arcs
// once (labels read 16x total), accumulates W[c][p] in LDS, emits one full
// kb-slab of the bf16 B-fragment layout Wf[kb][n][kin] (kb=c>>5, kin=c&31),
// AND rowsumW[c] = sum_p W[c][p] (lets the GEMM kernel compute the
// redistribution term per-row without any cross-column reduction).
// ---------------------------------------------------------------------------
__global__ __launch_bounds__(256) void build_Wf(const float* __restrict__ alloW,
                                                const int* __restrict__ phone_lab,
                                                const int* __restrict__ phoneme_lab,
                                                unsigned short* __restrict__ Wf,
                                                float* __restrict__ rowsumW) {
    __shared__ float wrow[32 * PDIM];   // 32 KB: [phone-within-block][phoneme]
    const int bx = blockIdx.x;          // 0..15 == kb
    const int t  = threadIdx.x;

#pragma unroll
    for (int i = 0; i < 32; ++i) wrow[i * 256 + t] = 0.0f;
    __syncthreads();

#pragma unroll
    for (int i = 0; i < ADIM / 256; ++i) {
        int a = i * 256 + t;
        int c = phone_lab[a];
        if ((c >> 5) == bx)
            atomicAdd(&wrow[(c & 31) * 256 + phoneme_lab[a]], __expf(alloW[a]));
    }
    __syncthreads();

    // thread t emits phoneme n=t: Wf[bx][t][0..31] (64 B contiguous)
    ushort8 pk[4];
#pragma unroll
    for (int g = 0; g < 4; ++g) {
#pragma unroll
        for (int j = 0; j < 8; ++j)
            pk[g][j] = bf16_rne(wrow[(g * 8 + j) * 256 + t]);
    }
    unsigned short* dst = Wf + (size_t)bx * (PDIM * 32) + t * 32;
#pragma unroll
    for (int g = 0; g < 4; ++g)
        *(ushort8*)(dst + g * 8) = pk[g];

    // rowsumW: row i = t>>3 (0..31), lane j = t&7 sums 32 phonemes
    {
        const int i = t >> 3, j = t & 7;
        float s = 0.0f;
#pragma unroll
        for (int m = 0; m < 32; ++m) s += wrow[i * 256 + j * 32 + m];
        s += __shfl_xor(s, 1);
        s += __shfl_xor(s, 2);
        s += __shfl_xor(s, 4);
        if (j == 0) rowsumW[bx * 32 + i] = s;
    }
}

// ---------------------------------------------------------------------------
// Kernel 2: fused exp + GEMM + redistribute + log — NO LDS, NO BARRIERS.
// Block: 256 thr (4 waves), tile 32 rows x 256 cols, grid 512 (2 blocks/CU).
// Wave w owns cols w*64..+63; all waves cover rows 0..31 (rb=0/1).
//
// Per kb, lane (c=lane&15, q=lane>>4) loads its OWN A-operand slice straight
// from global hs (A[m=c][k=q*8+j] -> 2x float4 of row row0+c / row0+16+c),
// exps + bf16-packs in-register, and accumulates per-lane partials of
// Z = sum_c e and Sw = sum_c e*rowsumW[c]. B from global Wf (frag-major,
// L2-hot). hs re-reads (4 waves, same rows) hit L1.
//
// Post-loop: shfl_xor(16,32) reduces Z/Sw over the q-quads; 16 __shfl's
// transpose (invZ,corr) from c-indexed lanes to the C/D layout's q-indexed
// rows (row = q*4+reg). Waves retire fully independently.
// ---------------------------------------------------------------------------
__global__ __launch_bounds__(256, 2) void allo_fused(const float* __restrict__ hs,
                                                     const unsigned short* __restrict__ Wf,
                                                     const float* __restrict__ rowsumW,
                                                     float* __restrict__ out) {
    const int tid  = threadIdx.x;
    const int wave = tid >> 6;
    const int lane = tid & 63;
    const int c    = lane & 15;
    const int q    = lane >> 4;
    const int row0 = blockIdx.x * 32;

    const float* hsr0 = hs + (size_t)(row0 + c) * CDIM + q * 8;
    const float* hsr1 = hsr0 + (size_t)16 * CDIM;
    const float* rsw  = rowsumW + q * 8;
    const unsigned short* wb = Wf + (size_t)(wave * 64 + c) * 32 + q * 8;

    f32x4 acc[2][4];
#pragma unroll
    for (int rb = 0; rb < 2; ++rb)
#pragma unroll
        for (int cb = 0; cb < 4; ++cb)
            acc[rb][cb] = (f32x4){0.f, 0.f, 0.f, 0.f};

    float z0 = 0.f, z1 = 0.f, sw0 = 0.f, sw1 = 0.f;

#pragma unroll 4
    for (int kb = 0; kb < 16; ++kb) {
        const int koff = kb * 32;
        float4 v00 = *(const float4*)(hsr0 + koff);
        float4 v01 = *(const float4*)(hsr0 + koff + 4);
        float4 v10 = *(const float4*)(hsr1 + koff);
        float4 v11 = *(const float4*)(hsr1 + koff + 4);
        float4 w0  = *(const float4*)(rsw + koff);
        float4 w1  = *(const float4*)(rsw + koff + 4);

        const unsigned short* wkb = wb + (size_t)kb * 8192;
        short8 b0 = *(const short8*)(wkb);
        short8 b1 = *(const short8*)(wkb + 512);
        short8 b2 = *(const short8*)(wkb + 1024);
        short8 b3 = *(const short8*)(wkb + 1536);

        float e00 = __expf(v00.x), e01 = __expf(v00.y);
        float e02 = __expf(v00.z), e03 = __expf(v00.w);
        float e04 = __expf(v01.x), e05 = __expf(v01.y);
        float e06 = __expf(v01.z), e07 = __expf(v01.w);
        z0 += ((e00 + e01) + (e02 + e03)) + ((e04 + e05) + (e06 + e07));
        sw0 = fmaf(e00, w0.x, sw0); sw0 = fmaf(e01, w0.y, sw0);
        sw0 = fmaf(e02, w0.z, sw0); sw0 = fmaf(e03, w0.w, sw0);
        sw0 = fmaf(e04, w1.x, sw0); sw0 = fmaf(e05, w1.y, sw0);
        sw0 = fmaf(e06, w1.z, sw0); sw0 = fmaf(e07, w1.w, sw0);

        float e10 = __expf(v10.x), e11 = __expf(v10.y);
        float e12 = __expf(v10.z), e13 = __expf(v10.w);
        float e14 = __expf(v11.x), e15 = __expf(v11.y);
        float e16 = __expf(v11.z), e17 = __expf(v11.w);
        z1 += ((e10 + e11) + (e12 + e13)) + ((e14 + e15) + (e16 + e17));
        sw1 = fmaf(e10, w0.x, sw1); sw1 = fmaf(e11, w0.y, sw1);
        sw1 = fmaf(e12, w0.z, sw1); sw1 = fmaf(e13, w0.w, sw1);
        sw1 = fmaf(e14, w1.x, sw1); sw1 = fmaf(e15, w1.y, sw1);
        sw1 = fmaf(e16, w1.z, sw1); sw1 = fmaf(e17, w1.w, sw1);

        short8 a0, a1;
        a0[0] = (short)bf16_rne(e00); a0[1] = (short)bf16_rne(e01);
        a0[2] = (short)bf16_rne(e02); a0[3] = (short)bf16_rne(e03);
        a0[4] = (short)bf16_rne(e04); a0[5] = (short)bf16_rne(e05);
        a0[6] = (short)bf16_rne(e06); a0[7] = (short)bf16_rne(e07);
        a1[0] = (short)bf16_rne(e10); a1[1] = (short)bf16_rne(e11);
        a1[2] = (short)bf16_rne(e12); a1[3] = (short)bf16_rne(e13);
        a1[4] = (short)bf16_rne(e14); a1[5] = (short)bf16_rne(e15);
        a1[6] = (short)bf16_rne(e16); a1[7] = (short)bf16_rne(e17);

        acc[0][0] = __builtin_amdgcn_mfma_f32_16x16x32_bf16(a0, b0, acc[0][0], 0, 0, 0);
        acc[0][1] = __builtin_amdgcn_mfma_f32_16x16x32_bf16(a0, b1, acc[0][1], 0, 0, 0);
        acc[0][2] = __builtin_amdgcn_mfma_f32_16x16x32_bf16(a0, b2, acc[0][2], 0, 0, 0);
        acc[0][3] = __builtin_amdgcn_mfma_f32_16x16x32_bf16(a0, b3, acc[0][3], 0, 0, 0);
        acc[1][0] = __builtin_amdgcn_mfma_f32_16x16x32_bf16(a1, b0, acc[1][0], 0, 0, 0);
        acc[1][1] = __builtin_amdgcn_mfma_f32_16x16x32_bf16(a1, b1, acc[1][1], 0, 0, 0);
        acc[1][2] = __builtin_amdgcn_mfma_f32_16x16x32_bf16(a1, b2, acc[1][2], 0, 0, 0);
        acc[1][3] = __builtin_amdgcn_mfma_f32_16x16x32_bf16(a1, b3, acc[1][3], 0, 0, 0);
    }

    // ---- reduce Z/Sw over the 4 q-quads (lanes xor 16, 32) ----
    z0  += __shfl_xor(z0, 16);  z0  += __shfl_xor(z0, 32);
    z1  += __shfl_xor(z1, 16);  z1  += __shfl_xor(z1, 32);
    sw0 += __shfl_xor(sw0, 16); sw0 += __shfl_xor(sw0, 32);
    sw1 += __shfl_xor(sw1, 16); sw1 += __shfl_xor(sw1, 32);

    const float iz0 = 1.0f / z0;                      // for row row0 + c
    const float co0 = (sw0 * iz0 - 1.0f) * (1.0f / (float)PDIM);
    const float iz1 = 1.0f / z1;                      // for row row0 + 16 + c
    const float co1 = (sw1 * iz1 - 1.0f) * (1.0f / (float)PDIM);

    // ---- transpose (invZ,corr) from c-indexed lanes to q-indexed rows ----
    // C/D mapping (m89/m91): col = lane&15 (=c), row = q*4 + reg.
    // Row value q*4+r lives in lane q*4+r (where c' = q*4+r).
    float izA[4], coA[4], izB[4], coB[4];
#pragma unroll
    for (int r = 0; r < 4; ++r) {
        const int src = q * 4 + r;
        izA[r] = __shfl(iz0, src); coA[r] = __shfl(co0, src);
        izB[r] = __shfl(iz1, src); coB[r] = __shfl(co1, src);
    }

    // ---- epilogue: per-lane log + store ----
#pragma unroll
    for (int r = 0; r < 4; ++r) {
        const int rr = q * 4 + r;
        float* orow0 = out + (size_t)(row0 + rr) * PDIM + wave * 64 + c;
        float* orow1 = out + (size_t)(row0 + 16 + rr) * PDIM + wave * 64 + c;
#pragma unroll
        for (int cb = 0; cb < 4; ++cb) {
            orow0[cb * 16] = __logf(acc[0][cb][r] * izA[r] - coA[r]);
            orow1[cb * 16] = __logf(acc[1][cb][r] * izB[r] - coB[r]);
        }
    }
}

// ---------------------------------------------------------------------------
extern "C" void kernel_launch(void* const* d_in, const int* in_sizes, int n_in,
                              void* d_out, int out_size, void* d_ws, size_t ws_size,
                              hipStream_t stream) {
    const float* hs          = (const float*)d_in[0];  // [BT, C]
    const float* alloW       = (const float*)d_in[1];  // [A]
    const int*   phone_lab   = (const int*)d_in[2];    // [A]
    const int*   phoneme_lab = (const int*)d_in[3];    // [A]
    float*       out         = (float*)d_out;          // [BT, P]

    // ws: Wf 256 KB at 0, rowsumW 2 KB after
    unsigned short* Wf      = (unsigned short*)d_ws;
    float*          rowsumW = (float*)((char*)d_ws + (256 << 10));

    build_Wf<<<CDIM / 32, 256, 0, stream>>>(alloW, phone_lab, phoneme_lab, Wf, rowsumW);
    allo_fused<<<BT / 32, 256, 0, stream>>>(hs, Wf, rowsumW, out);
}